// Round 9
// baseline (365.018 us; speedup 1.0000x reference)
//
#include <hip/hip_runtime.h>
#include <cstdint>
#include <cstddef>

#define B_   128
#define NF_  64
#define L_   4096
#define K_   64
#define NG_  400

#define GP_     8                 // g partitions (grid.x): 512 blocks = 2/CU
#define GITER_  (NG_ / GP_)       // 50 g-tiles per block
#define ROWS_   2                 // batch rows per block (weight amortization)
#define PADF_   128               // zero pad each side (window overhang <= 99)
#define ROWPF_  (PADF_ + L_ + PADF_)   // 4352 floats per padded row

constexpr float STEP = 4096.0f / 4095.0f;              // linspace(0,4096,4096) step
constexpr float NEGC = -1.4426950408889634f / 512.0f;  // -log2(e)/(2*sigma^2), sigma=16

// ---------------------------------------------------------------------------
// Persistent filter kernel = R4 structure + depth-2 register prefetch +
// counted-wait barrier (lgkmcnt(0)+s_barrier, NOT __syncthreads' vmcnt(0)).
// Block = (g-partition p, batch pair b0). 512 thr = 64 filters x 8 f4-slots.
// Double-buffered LDS 2x2x17.4KB = 69.6KB -> 2 blocks/CU, 16 waves/CU.
// Pipeline at iter i: LDS[cur]=tile i (compute), regsW=tile i+1 (ds_write at
// end of i), regsI=tile i+2 (loads ISSUED at top of i, in flight across the
// barrier -> HBM never drains).
// ---------------------------------------------------------------------------
__global__ __launch_bounds__(512, 4) void filt_kernel(
    const float* __restrict__ X, const float* __restrict__ mus,
    const float* __restrict__ amps, float* __restrict__ part)
{
    const int p  = blockIdx.x;
    const int b0 = blockIdx.y * ROWS_;
    const int t  = threadIdx.x;
    const int f  = t >> 3;        // filter 0..63
    const int i8 = t & 7;         // window float4 slot 0..7

    __shared__ __align__(16) float Xs[2][ROWS_][ROWPF_];

    // zero the pads of both buffers once (32 f4 front + 32 f4 back per row)
    if (t < 256) {
        const int br = t >> 6;            // (buf,row) 0..3
        const int k  = t & 63;
        float4* pr = (float4*)Xs[br >> 1][br & 1];
        const float4 z{0.f, 0.f, 0.f, 0.f};
        if (k < 32) pr[k] = z;
        else        pr[1056 + (k - 32)] = z;   // 4224/4 = 1056
    }

    const float* __restrict__ Xb0 = X + ((size_t)(b0 + 0) * NG_) * L_;
    const float* __restrict__ Xb1 = X + ((size_t)(b0 + 1) * NG_) * L_;
    const int gs = p * GITER_;

    float4 xvA[4], xvB[4];

#define LOADT(xv, g) {                                                   \
        const float4* r0 = (const float4*)(Xb0 + (size_t)(g) * L_);      \
        const float4* r1 = (const float4*)(Xb1 + (size_t)(g) * L_);      \
        xv[0] = r0[t]; xv[1] = r0[t + 512];                              \
        xv[2] = r1[t]; xv[3] = r1[t + 512]; }

#define WRITET(xv, buf) {                                                \
        float4* e0 = (float4*)(Xs[buf][0] + PADF_);                      \
        float4* e1 = (float4*)(Xs[buf][1] + PADF_);                      \
        e0[t] = xv[0]; e0[t + 512] = xv[1];                              \
        e1[t] = xv[2]; e1[t + 512] = xv[3]; }

#define BARRIER() {                                                      \
        asm volatile("s_waitcnt lgkmcnt(0)" ::: "memory");               \
        __builtin_amdgcn_s_barrier();                                    \
        __builtin_amdgcn_sched_barrier(0); }

    // ---- prologue: tile0 -> LDS[0]; tile1 in xvB; mu/sc(g0) in regs ----
    LOADT(xvA, gs + 0);
    float mu_c = mus [f * NG_ + gs];
    float sc_c = amps[f * NG_ + gs] * (1.0f / 4096.0f);
    LOADT(xvB, gs + 1);
    WRITET(xvA, 0);               // compiler waits only the A-loads (counted)
    BARRIER();

    float acc0 = 0.f, acc1 = 0.f;

    // body(it): compute tile it from LDS[it&1]; issue loads it+2 into regsI;
    // ds_write regsW (tile it+1) -> LDS[(it+1)&1]; counted barrier.
#define BODY(it, regsI, regsW) {                                         \
        if ((it) + 2 < GITER_) LOADT(regsI, gs + (it) + 2);              \
        const float mu = mu_c;                                           \
        const float sc = sc_c;                                           \
        {   const int gn = gs + (((it) + 1 < GITER_) ? (it) + 1 : (it)); \
            mu_c = mus [f * NG_ + gn];                                   \
            sc_c = amps[f * NG_ + gn] * (1.0f / 4096.0f); }              \
        const int   l0 = (((int)mu) - 96) & ~3;                          \
        const float bx = fmaf((float)(l0 + 4 * i8), STEP, -mu);          \
        float wgt[6][4];                                                 \
        _Pragma("unroll")                                                \
        for (int c = 0; c < 6; ++c)                                      \
            _Pragma("unroll")                                            \
            for (int j = 0; j < 4; ++j) {                                \
                const float d = bx + (float)(32 * c + j) * STEP;         \
                wgt[c][j] = exp2f(NEGC * d * d);                         \
            }                                                            \
        const float* x0 = Xs[(it) & 1][0] + PADF_ + l0 + 4 * i8;         \
        const float* x1 = Xs[(it) & 1][1] + PADF_ + l0 + 4 * i8;         \
        float d0 = 0.f, d1 = 0.f;                                        \
        _Pragma("unroll")                                                \
        for (int c = 0; c < 6; ++c) {                                    \
            const float4 a = *(const float4*)(x0 + 32 * c);              \
            const float4 b = *(const float4*)(x1 + 32 * c);              \
            d0 = fmaf(a.x, wgt[c][0], fmaf(a.y, wgt[c][1],               \
                 fmaf(a.z, wgt[c][2], fmaf(a.w, wgt[c][3], d0))));       \
            d1 = fmaf(b.x, wgt[c][0], fmaf(b.y, wgt[c][1],               \
                 fmaf(b.z, wgt[c][2], fmaf(b.w, wgt[c][3], d1))));       \
        }                                                                \
        acc0 = fmaf(sc, d0, acc0);                                       \
        acc1 = fmaf(sc, d1, acc1);                                       \
        if ((it) + 1 < GITER_) { WRITET(regsW, ((it) + 1) & 1); BARRIER(); } }

    for (int it = 0; it < GITER_; it += 2) {
        BODY(it,     xvA, xvB);   // even: issue into A, write B (tile it+1)
        BODY(it + 1, xvB, xvA);   // odd : issue into B, write A
    }

    // reduce across the 8 lanes sharing this filter (consecutive lanes)
#pragma unroll
    for (int d = 1; d < 8; d <<= 1) {
        acc0 += __shfl_xor(acc0, d);
        acc1 += __shfl_xor(acc1, d);
    }
    if (i8 == 0) {
        part[((size_t)p * B_ + b0    ) * NF_ + f] = acc0;
        part[((size_t)p * B_ + b0 + 1) * NF_ + f] = acc1;
    }
#undef LOADT
#undef WRITET
#undef BARRIER
#undef BODY
}

// ---------------------------------------------------------------------------
// MLP head: sums GP_ partials, elu/reparam + 3 small GEMVs (exact gelu).
// grid (B_, 4): q-slice owns 100 of 400 output gaussians; front recomputed
// per slice, q==0 stores mu/log_sig.
// out layout: coms[128*400] | pred[128*400] | mu[128*64] | log_sig[128*64]
// ---------------------------------------------------------------------------
__device__ __forceinline__ float gelu_exact(float x) {
    return 0.5f * x * (1.0f + erff(x * 0.70710678118654752f));
}

__global__ __launch_bounds__(256) void head_kernel(
    const float* __restrict__ part, const float* __restrict__ eps,
    const float* __restrict__ Wmu,  const float* __restrict__ bmu,
    const float* __restrict__ Wsig, const float* __restrict__ bsig,
    const float* __restrict__ W01,  const float* __restrict__ b01,
    const float* __restrict__ W1,   const float* __restrict__ b1,
    const float* __restrict__ W2,   const float* __restrict__ b2,
    float* __restrict__ out)
{
    const int b = blockIdx.x;
    const int q = blockIdx.y;
    const int t = threadIdx.x;
    __shared__ float fil[NF_], lat[K_], hh[K_];

    if (t < NF_) {
        float s = 0.f;
#pragma unroll
        for (int pp = 0; pp < GP_; ++pp)
            s += part[((size_t)pp * B_ + b) * NF_ + t];
        fil[t] = s;
    }
    __syncthreads();

    if (t < K_) {
        float am = bmu[t], as = bsig[t];
#pragma unroll 8
        for (int fj = 0; fj < NF_; ++fj) {
            float x = fil[fj];
            am = fmaf(x, Wmu [t * NF_ + fj], am);
            as = fmaf(x, Wsig[t * NF_ + fj], as);
        }
        float muv = am > 0.0f ? am : expm1f(am);
        float lsv = as > 0.0f ? as : expm1f(as);
        if (q == 0) {
            out[2 * B_ * NG_            + b * K_ + t] = muv;   // mu
            out[2 * B_ * NG_ + B_ * K_  + b * K_ + t] = lsv;   // log_sig
        }
        lat[t] = fmaf(eps[b * K_ + t], expf(lsv), muv);
    }
    __syncthreads();

    if (t < K_) {
        float a = b01[t];
#pragma unroll 8
        for (int j = 0; j < K_; ++j) a = fmaf(lat[j], W01[t * K_ + j], a);
        hh[t] = gelu_exact(a);
    }
    __syncthreads();

    const int n0 = q * 100, n1 = n0 + 100;
    for (int n = n0 + t; n < n1; n += 256) {
        float a1 = b1[n], a2 = b2[n];
#pragma unroll 8
        for (int k = 0; k < K_; ++k) {
            float hk = hh[k];
            a1 = fmaf(hk, W1[n * K_ + k], a1);
            a2 = fmaf(hk, W2[n * K_ + k], a2);
        }
        out[            b * NG_ + n] = gelu_exact(a1);   // coms
        out[B_ * NG_ +  b * NG_ + n] = gelu_exact(a2);   // pred_num_spikes
    }
}

extern "C" void kernel_launch(void* const* d_in, const int* in_sizes, int n_in,
                              void* d_out, int out_size, void* d_ws, size_t ws_size,
                              hipStream_t stream) {
    const float* X    = (const float*)d_in[0];
    const float* eps  = (const float*)d_in[1];
    const float* mus  = (const float*)d_in[2];
    const float* amps = (const float*)d_in[3];
    const float* Wmu  = (const float*)d_in[4];
    const float* bmu  = (const float*)d_in[5];
    const float* Wsig = (const float*)d_in[6];
    const float* bsig = (const float*)d_in[7];
    const float* W01  = (const float*)d_in[8];
    const float* b01  = (const float*)d_in[9];
    const float* W1   = (const float*)d_in[10];
    const float* b1   = (const float*)d_in[11];
    const float* W2   = (const float*)d_in[12];
    const float* b2   = (const float*)d_in[13];

    float* out  = (float*)d_out;
    float* part = (float*)d_ws;   // GP_*B_*NF_ f32 partials (fully overwritten)

    filt_kernel<<<dim3(GP_, B_ / ROWS_), 512, 0, stream>>>(X, mus, amps, part);
    head_kernel<<<dim3(B_, 4), 256, 0, stream>>>(part, eps, Wmu, bmu, Wsig, bsig,
                                                 W01, b01, W1, b1, W2, b2, out);
}

// Round 10
// 289.665 us; speedup vs baseline: 1.2601x; 1.2601x over previous
//
#include <hip/hip_runtime.h>
#include <cstdint>
#include <cstddef>

#define B_   128
#define NF_  64
#define L_   4096
#define K_   64
#define NG_  400

constexpr float STEP = 4096.0f / 4095.0f;              // linspace(0,4096,4096) step
constexpr float NEGC = -1.4426950408889634f / 512.0f;  // -log2(e)/(2*sigma^2), sigma=16

// ---------------------------------------------------------------------------
// Direct-from-global filter kernel. No LDS, no barriers, no staging.
// Block = one (b,g) row; 512 thr = 64 filters x 8 float4-slots.
// The 16KB row is pulled through L1 (fits 32KB); each element is read ~3x
// on average (64 windows x 192 / 4096) — L1/L2 absorb the amplification,
// HBM sees each line once. Out-of-row samples get weight 0 via an unsigned
// l-compare (replaces LDS zero-padding and kills neighbor-row bleed);
// float4 indices are clamped to the allocation so the two extreme rows
// can't fault (clamped f4s are always fully masked).
// 8-lane shuffle reduce -> one atomicAdd per (b,f,g).
// ---------------------------------------------------------------------------
__global__ __launch_bounds__(512, 6) void filt_kernel(
    const float* __restrict__ X, const float* __restrict__ mus,
    const float* __restrict__ amps, float* __restrict__ filtered)
{
    const int g  = blockIdx.x;
    const int b  = blockIdx.y;
    const int t  = threadIdx.x;
    const int f  = t >> 3;        // filter 0..63
    const int i8 = t & 7;         // window float4 slot 0..7

    const float mu = mus [f * NG_ + g];
    const float sc = amps[f * NG_ + g] * (1.0f / 4096.0f);
    const int   l0 = (((int)mu) - 96) & ~3;        // 16B-aligned window start

    // ---- 24 window weights, validity-masked (l must be in [0,4096)) ----
    const int   lb = l0 + 4 * i8;                  // this thread's first l
    const float bx = fmaf((float)lb, STEP, -mu);
    float wgt[6][4];
#pragma unroll
    for (int c = 0; c < 6; ++c)
#pragma unroll
        for (int j = 0; j < 4; ++j) {
            const float d = bx + (float)(32 * c + j) * STEP;
            const float w = exp2f(NEGC * d * d);
            const int   l = lb + 32 * c + j;
            wgt[c][j] = ((unsigned)l < 4096u) ? w : 0.0f;
        }

    // ---- windowed dot, reading straight from global (L1-resident row) ----
    const int rowF4 = ((b * NG_ + g) * L_ + l0) >> 2;   // exact: l0 4-aligned
    const int MAXI  = B_ * NG_ * (L_ / 4) - 1;          // last valid f4 index
    const float4* __restrict__ X4 = (const float4*)X;

    float dsum = 0.0f;
#pragma unroll
    for (int c = 0; c < 6; ++c) {
        int idx = rowF4 + i8 + 8 * c;
        idx = idx < 0 ? 0 : (idx > MAXI ? MAXI : idx);  // allocation guard
        const float4 a = X4[idx];
        dsum = fmaf(a.x, wgt[c][0], fmaf(a.y, wgt[c][1],
               fmaf(a.z, wgt[c][2], fmaf(a.w, wgt[c][3], dsum))));
    }

    // ---- reduce the 8 consecutive lanes sharing this filter ----
#pragma unroll
    for (int d = 1; d < 8; d <<= 1) dsum += __shfl_xor(dsum, d);
    if (i8 == 0) atomicAdd(&filtered[b * NF_ + f], sc * dsum);
}

// ---------------------------------------------------------------------------
// MLP head: elu/reparam + 3 small GEMVs (exact gelu).
// grid (B_, 4): q-slice owns 100 of 400 output gaussians; front recomputed
// per slice, q==0 stores mu/log_sig.
// out layout: coms[128*400] | pred[128*400] | mu[128*64] | log_sig[128*64]
// ---------------------------------------------------------------------------
__device__ __forceinline__ float gelu_exact(float x) {
    return 0.5f * x * (1.0f + erff(x * 0.70710678118654752f));
}

__global__ __launch_bounds__(256) void head_kernel(
    const float* __restrict__ filtered, const float* __restrict__ eps,
    const float* __restrict__ Wmu,  const float* __restrict__ bmu,
    const float* __restrict__ Wsig, const float* __restrict__ bsig,
    const float* __restrict__ W01,  const float* __restrict__ b01,
    const float* __restrict__ W1,   const float* __restrict__ b1,
    const float* __restrict__ W2,   const float* __restrict__ b2,
    float* __restrict__ out)
{
    const int b = blockIdx.x;
    const int q = blockIdx.y;
    const int t = threadIdx.x;
    __shared__ float fil[NF_], lat[K_], hh[K_];

    if (t < NF_) fil[t] = filtered[b * NF_ + t];
    __syncthreads();

    if (t < K_) {
        float am = bmu[t], as = bsig[t];
#pragma unroll 8
        for (int fj = 0; fj < NF_; ++fj) {
            float x = fil[fj];
            am = fmaf(x, Wmu [t * NF_ + fj], am);
            as = fmaf(x, Wsig[t * NF_ + fj], as);
        }
        float muv = am > 0.0f ? am : expm1f(am);
        float lsv = as > 0.0f ? as : expm1f(as);
        if (q == 0) {
            out[2 * B_ * NG_            + b * K_ + t] = muv;   // mu
            out[2 * B_ * NG_ + B_ * K_  + b * K_ + t] = lsv;   // log_sig
        }
        lat[t] = fmaf(eps[b * K_ + t], expf(lsv), muv);
    }
    __syncthreads();

    if (t < K_) {
        float a = b01[t];
#pragma unroll 8
        for (int j = 0; j < K_; ++j) a = fmaf(lat[j], W01[t * K_ + j], a);
        hh[t] = gelu_exact(a);
    }
    __syncthreads();

    const int n0 = q * 100, n1 = n0 + 100;
    for (int n = n0 + t; n < n1; n += 256) {
        float a1 = b1[n], a2 = b2[n];
#pragma unroll 8
        for (int k = 0; k < K_; ++k) {
            float hk = hh[k];
            a1 = fmaf(hk, W1[n * K_ + k], a1);
            a2 = fmaf(hk, W2[n * K_ + k], a2);
        }
        out[            b * NG_ + n] = gelu_exact(a1);   // coms
        out[B_ * NG_ +  b * NG_ + n] = gelu_exact(a2);   // pred_num_spikes
    }
}

extern "C" void kernel_launch(void* const* d_in, const int* in_sizes, int n_in,
                              void* d_out, int out_size, void* d_ws, size_t ws_size,
                              hipStream_t stream) {
    const float* X    = (const float*)d_in[0];
    const float* eps  = (const float*)d_in[1];
    const float* mus  = (const float*)d_in[2];
    const float* amps = (const float*)d_in[3];
    const float* Wmu  = (const float*)d_in[4];
    const float* bmu  = (const float*)d_in[5];
    const float* Wsig = (const float*)d_in[6];
    const float* bsig = (const float*)d_in[7];
    const float* W01  = (const float*)d_in[8];
    const float* b01  = (const float*)d_in[9];
    const float* W1   = (const float*)d_in[10];
    const float* b1   = (const float*)d_in[11];
    const float* W2   = (const float*)d_in[12];
    const float* b2   = (const float*)d_in[13];

    float* out      = (float*)d_out;
    float* filtered = (float*)d_ws;   // B_*NF_ f32 atomic accumulator

    // zero the atomic accumulator every call (harness does not re-poison)
    hipMemsetAsync(filtered, 0, B_ * NF_ * sizeof(float), stream);

    filt_kernel<<<dim3(NG_, B_), 512, 0, stream>>>(X, mus, amps, filtered);
    head_kernel<<<dim3(B_, 4), 256, 0, stream>>>(filtered, eps, Wmu, bmu, Wsig, bsig,
                                                 W01, b01, W1, b1, W2, b2, out);
}

// Round 11
// 160.532 us; speedup vs baseline: 2.2738x; 1.8044x over previous
//
#include <hip/hip_runtime.h>
#include <cstdint>
#include <cstddef>

#define B_   128
#define NF_  64
#define L_   4096
#define K_   64
#define NG_  400

#define GP_     8                 // g partitions (grid.x): 512 blocks = 2/CU
#define GITER_  (NG_ / GP_)       // 50 g-tiles per block
#define ROWS_   2                 // batch rows per block (weight amortization)
#define PADF_   128               // zero pad each side (window overhang <= 99)
#define ROWPF_  (PADF_ + L_ + PADF_)   // 4352 floats per padded row

constexpr float STEP = 4096.0f / 4095.0f;              // linspace(0,4096,4096) step
constexpr float NEGC = -1.4426950408889634f / 512.0f;  // -log2(e)/(2*sigma^2), sigma=16

// ---------------------------------------------------------------------------
// R4's proven structure (reg-staged LDS, double buffer, ONE __syncthreads per
// tile) at DOUBLE the wave count: 1024-thread blocks, 64 filters x 16 lanes.
// Per-CU totals (bytes staged, LDS ops, exp2 count) are identical to R4;
// per-thread work is halved -> ~40 VGPR -> 8 waves/SIMD (32 waves/CU) with
// __launch_bounds__(1024,8). More independent waves fill the vmcnt-stall
// bubbles that left R4 at ~84% of achievable HBM BW.
// Pipeline at iter i: LDS[i&1] = tile i (compute); loads for tile i+1 issued
// at top of iter i; ds_write + barrier at the bottom.
// ---------------------------------------------------------------------------
__global__ __launch_bounds__(1024, 8) void filt_kernel(
    const float* __restrict__ X, const float* __restrict__ mus,
    const float* __restrict__ amps, float* __restrict__ part)
{
    const int p   = blockIdx.x;
    const int b0  = blockIdx.y * ROWS_;
    const int t   = threadIdx.x;
    const int f   = t >> 4;       // filter 0..63
    const int i16 = t & 15;       // window float4 slot 0..15 (3 f4 each)

    __shared__ __align__(16) float Xs[2][ROWS_][ROWPF_];

    // zero the pads of both buffers once (32 f4 front + 32 f4 back per row)
    if (t < 256) {
        const int br = t >> 6;            // (buf,row) 0..3
        const int k  = t & 63;
        float4* pr = (float4*)Xs[br >> 1][br & 1];
        const float4 z{0.f, 0.f, 0.f, 0.f};
        if (k < 32) pr[k] = z;
        else        pr[1056 + (k - 32)] = z;   // (PADF_+L_)/4 = 1056
    }

    const float* __restrict__ Xb0 = X + ((size_t)(b0 + 0) * NG_) * L_;
    const float* __restrict__ Xb1 = X + ((size_t)(b0 + 1) * NG_) * L_;
    const int gs = p * GITER_;

    // ---- prologue: tile 0 -> LDS[0]; mu/sc(g0) in regs ----
    float4 xv0 = ((const float4*)(Xb0 + (size_t)gs * L_))[t];
    float4 xv1 = ((const float4*)(Xb1 + (size_t)gs * L_))[t];
    float mu_c = mus [f * NG_ + gs];
    float sc_c = amps[f * NG_ + gs] * (1.0f / 4096.0f);
    ((float4*)(Xs[0][0] + PADF_))[t] = xv0;
    ((float4*)(Xs[0][1] + PADF_))[t] = xv1;
    __syncthreads();

    float acc0 = 0.f, acc1 = 0.f;

    for (int it = 0; it < GITER_; ++it) {
        const int  cur  = it & 1;
        const bool more = (it + 1 < GITER_);
        const int  g    = gs + it;

        // issue next tile's loads FIRST (latency hides under compute)
        if (more) {
            xv0 = ((const float4*)(Xb0 + (size_t)(g + 1) * L_))[t];
            xv1 = ((const float4*)(Xb1 + (size_t)(g + 1) * L_))[t];
        }
        const float mu = mu_c;
        const float sc = sc_c;
        if (more) {                       // one-iter-ahead scalar prefetch
            mu_c = mus [f * NG_ + g + 1];
            sc_c = amps[f * NG_ + g + 1] * (1.0f / 4096.0f);
        }

        // 12 Gaussian window weights + windowed dot for both rows.
        // 16 consecutive lanes read 16 consecutive float4 (256B) -> each
        // bank exactly twice = free 2-way aliasing (m136).
        const int   l0 = (((int)mu) - 96) & ~3;        // 16B-aligned start
        const float bx = fmaf((float)(l0 + 4 * i16), STEP, -mu);
        const float* x0 = Xs[cur][0] + PADF_ + l0 + 4 * i16;
        const float* x1 = Xs[cur][1] + PADF_ + l0 + 4 * i16;
        float d0 = 0.f, d1 = 0.f;
#pragma unroll
        for (int c = 0; c < 3; ++c) {
            float w[4];
#pragma unroll
            for (int j = 0; j < 4; ++j) {
                const float d = bx + (float)(64 * c + j) * STEP;
                w[j] = exp2f(NEGC * d * d);
            }
            const float4 a = *(const float4*)(x0 + 64 * c);
            const float4 b = *(const float4*)(x1 + 64 * c);
            d0 = fmaf(a.x, w[0], fmaf(a.y, w[1], fmaf(a.z, w[2], fmaf(a.w, w[3], d0))));
            d1 = fmaf(b.x, w[0], fmaf(b.y, w[1], fmaf(b.z, w[2], fmaf(b.w, w[3], d1))));
        }
        acc0 = fmaf(sc, d0, acc0);
        acc1 = fmaf(sc, d1, acc1);

        // write next tile, single barrier (R4-proven)
        if (more) {
            ((float4*)(Xs[cur ^ 1][0] + PADF_))[t] = xv0;
            ((float4*)(Xs[cur ^ 1][1] + PADF_))[t] = xv1;
            __syncthreads();
        }
    }

    // reduce across the 16 consecutive lanes sharing this filter
#pragma unroll
    for (int d = 1; d < 16; d <<= 1) {
        acc0 += __shfl_xor(acc0, d);
        acc1 += __shfl_xor(acc1, d);
    }
    if (i16 == 0) {
        part[((size_t)p * B_ + b0    ) * NF_ + f] = acc0;
        part[((size_t)p * B_ + b0 + 1) * NF_ + f] = acc1;
    }
}

// ---------------------------------------------------------------------------
// MLP head: sums GP_ partials, elu/reparam + 3 small GEMVs (exact gelu).
// grid (B_, 4): q-slice owns 100 of 400 output gaussians; front recomputed
// per slice, q==0 stores mu/log_sig.
// out layout: coms[128*400] | pred[128*400] | mu[128*64] | log_sig[128*64]
// ---------------------------------------------------------------------------
__device__ __forceinline__ float gelu_exact(float x) {
    return 0.5f * x * (1.0f + erff(x * 0.70710678118654752f));
}

__global__ __launch_bounds__(256) void head_kernel(
    const float* __restrict__ part, const float* __restrict__ eps,
    const float* __restrict__ Wmu,  const float* __restrict__ bmu,
    const float* __restrict__ Wsig, const float* __restrict__ bsig,
    const float* __restrict__ W01,  const float* __restrict__ b01,
    const float* __restrict__ W1,   const float* __restrict__ b1,
    const float* __restrict__ W2,   const float* __restrict__ b2,
    float* __restrict__ out)
{
    const int b = blockIdx.x;
    const int q = blockIdx.y;
    const int t = threadIdx.x;
    __shared__ float fil[NF_], lat[K_], hh[K_];

    if (t < NF_) {
        float s = 0.f;
#pragma unroll
        for (int pp = 0; pp < GP_; ++pp)
            s += part[((size_t)pp * B_ + b) * NF_ + t];
        fil[t] = s;
    }
    __syncthreads();

    if (t < K_) {
        float am = bmu[t], as = bsig[t];
#pragma unroll 8
        for (int fj = 0; fj < NF_; ++fj) {
            float x = fil[fj];
            am = fmaf(x, Wmu [t * NF_ + fj], am);
            as = fmaf(x, Wsig[t * NF_ + fj], as);
        }
        float muv = am > 0.0f ? am : expm1f(am);
        float lsv = as > 0.0f ? as : expm1f(as);
        if (q == 0) {
            out[2 * B_ * NG_            + b * K_ + t] = muv;   // mu
            out[2 * B_ * NG_ + B_ * K_  + b * K_ + t] = lsv;   // log_sig
        }
        lat[t] = fmaf(eps[b * K_ + t], expf(lsv), muv);
    }
    __syncthreads();

    if (t < K_) {
        float a = b01[t];
#pragma unroll 8
        for (int j = 0; j < K_; ++j) a = fmaf(lat[j], W01[t * K_ + j], a);
        hh[t] = gelu_exact(a);
    }
    __syncthreads();

    const int n0 = q * 100, n1 = n0 + 100;
    for (int n = n0 + t; n < n1; n += 256) {
        float a1 = b1[n], a2 = b2[n];
#pragma unroll 8
        for (int k = 0; k < K_; ++k) {
            float hk = hh[k];
            a1 = fmaf(hk, W1[n * K_ + k], a1);
            a2 = fmaf(hk, W2[n * K_ + k], a2);
        }
        out[            b * NG_ + n] = gelu_exact(a1);   // coms
        out[B_ * NG_ +  b * NG_ + n] = gelu_exact(a2);   // pred_num_spikes
    }
}

extern "C" void kernel_launch(void* const* d_in, const int* in_sizes, int n_in,
                              void* d_out, int out_size, void* d_ws, size_t ws_size,
                              hipStream_t stream) {
    const float* X    = (const float*)d_in[0];
    const float* eps  = (const float*)d_in[1];
    const float* mus  = (const float*)d_in[2];
    const float* amps = (const float*)d_in[3];
    const float* Wmu  = (const float*)d_in[4];
    const float* bmu  = (const float*)d_in[5];
    const float* Wsig = (const float*)d_in[6];
    const float* bsig = (const float*)d_in[7];
    const float* W01  = (const float*)d_in[8];
    const float* b01  = (const float*)d_in[9];
    const float* W1   = (const float*)d_in[10];
    const float* b1   = (const float*)d_in[11];
    const float* W2   = (const float*)d_in[12];
    const float* b2   = (const float*)d_in[13];

    float* out  = (float*)d_out;
    float* part = (float*)d_ws;   // GP_*B_*NF_ f32 partials (fully overwritten)

    filt_kernel<<<dim3(GP_, B_ / ROWS_), 1024, 0, stream>>>(X, mus, amps, part);
    head_kernel<<<dim3(B_, 4), 256, 0, stream>>>(part, eps, Wmu, bmu, Wsig, bsig,
                                                 W01, b01, W1, b1, W2, b2, out);
}